// Round 5
// baseline (26.760 us; speedup 1.0000x reference)
//
#include <hip/hip_runtime.h>

// CenterLoss — R13: R10 (best measured, 25.27us) + LDS-prefetch bridge for the
// one machine-coherent memory-idle window (row 0 tail -> row 1 load issue).
//   (a) Row 1's chunks 0..2 prefetched via __builtin_amdgcn_global_load_lds
//       (async, ZERO VGPR cost — R9 showed register prefetch pays occupancy).
//       Issued right after row 0's chunk loads; consumed from LDS at row 1.
//       Each wave reads back only the LDS segment it wrote -> same-wave
//       dependency, no cross-wave sync needed; vmcnt(0) at row 1 top is
//       instant (prefetches are a full row old).
//   (b) Both __syncthreads replaced by {s_waitcnt lgkmcnt(0); raw s_barrier}.
//       __syncthreads' implicit vmcnt(0) would drain the prefetches at
//       barrier A and just MOVE the stall. Barriers only order sMax/sFi
//       (LDS), so lgkmcnt(0) is the full requirement (verified HK pattern).
// Kept (measured): 2048 blocks x RPB=2 (8 blocks/CU, 32 waves/CU, one
// generation); 7-deep per-thread load burst; no trailing barrier (R10);
// f/c gather in the wave-0 tail (R9: hoisting regressed); two-kernel
// store-and-reduce (same-address atomics +45us, acq-rel +165us).
// LDS: 3*256*16B = 12.3KB/block -> 98KB/CU at 8 blocks/CU (thread-limited,
// no occupancy change).
//
// loss = mean_n( clip(||f||^2 + ||c_lab||^2 - 2 f.c_lab, 1e-12, 1e12) ) + (C-1)*1e-12
// lab = argmax_c predicts[n, c]  (first occurrence on ties).

#define NC   6625
#define FD   96
#define NROW 4096
#define RPB  2      // rows per block

// Raw barrier: orders LDS only; does NOT drain vmcnt (keeps prefetch in flight).
__device__ __forceinline__ void sync_lds_only() {
    asm volatile("s_waitcnt lgkmcnt(0)" ::: "memory");
    __builtin_amdgcn_s_barrier();
}

// Async global->LDS, 16B per lane. gsrc is per-lane; ldst must be wave-uniform
// (HW writes base + lane*16).
#define GLOAD_LDS(gsrc, ldst)                                                  \
    __builtin_amdgcn_global_load_lds(                                          \
        (const __attribute__((address_space(1))) void*)(const void*)(gsrc),    \
        (__attribute__((address_space(3))) void*)(void*)(ldst), 16, 0, 0)

__global__ __launch_bounds__(256) void centerloss_row_kernel(
    const float* __restrict__ features,
    const float* __restrict__ predicts,
    const float* __restrict__ centers,
    float* __restrict__ row_out)
{
    const int t = threadIdx.x;
    const int w = t >> 6;          // wave id: 0..3 (uniform per wave)
    const float NEG_INF = -__builtin_huge_valf();

    __shared__ float  sMax[4];
    __shared__ int    sFi[4];
    __shared__ float4 sPre[3][256];   // prefetched chunks 0..2 of row 1

    #pragma unroll 1
    for (int r = 0; r < RPB; ++r) {
        const int n = blockIdx.x * RPB + r;
        const size_t base = (size_t)n * NC;
        const float* row = predicts + base;

        // Row start is only 4B-aligned (6625 % 4 == 1): scalar prologue to 16B.
        const int pro  = (int)((4 - (base & 3)) & 3);     // 0..3
        const int nvec = (NC - pro) >> 2;                 // 1655 or 1656
        const float4* vrow = (const float4*)(row + pro);

        // ---- Phase A: chunks 0..2 from LDS (row 1) or global (row 0) ----
        float4 v0, v1, v2;
        if (r == 1) {
            // Same-wave producer: this wave's prefetches are the only
            // outstanding vmem ops (all row-0 loads were consumed) -> instant.
            asm volatile("s_waitcnt vmcnt(0)" ::: "memory");
            v0 = sPre[0][t];
            v1 = sPre[1][t];
            v2 = sPre[2][t];
        } else {
            v0 = vrow[t];
            v1 = vrow[t +  256];
            v2 = vrow[t +  512];
        }
        // Chunks 3..5 unconditional: max idx 255+1280=1535 < min nvec=1655.
        const float4 v3 = vrow[t +  768];
        const float4 v4 = vrow[t + 1024];
        const float4 v5 = vrow[t + 1280];
        float4 v6 = make_float4(NEG_INF, NEG_INF, NEG_INF, NEG_INF);
        const int i6 = t + 1536;
        if (i6 < nvec) v6 = vrow[i6];                     // ~120 lanes valid

        float vpro = NEG_INF;
        if (t < pro) vpro = row[t];                       // idx = t
        const int tailStart = pro + 4 * nvec;
        float vtail = NEG_INF;
        if (t < NC - tailStart) vtail = row[tailStart + t];

        // ---- Prefetch row 1 chunks 0..2 into LDS (async, no VGPR cost).
        // Issued after this row's burst -> returns during this row's tail,
        // keeping the memory pipe busy through tree/barriers/rescan/gather.
        if (r == 0) {
            const size_t base1 = base + NC;
            const float* row1  = predicts + base1;
            const int    pro1  = (int)((4 - (base1 & 3)) & 3);
            const float4* vrow1 = (const float4*)(row1 + pro1);
            GLOAD_LDS(vrow1 + t,       &sPre[0][w * 64]);
            GLOAD_LDS(vrow1 + t + 256, &sPre[1][w * 64]);
            GLOAD_LDS(vrow1 + t + 512, &sPre[2][w * 64]);
        }

        // Thread max via fmax tree (fuses to v_max3_f32); no index tracking.
        float m = fmaxf(fmaxf(fmaxf(v0.x, v0.y), fmaxf(v0.z, v0.w)),
                        fmaxf(fmaxf(v1.x, v1.y), fmaxf(v1.z, v1.w)));
        m = fmaxf(m, fmaxf(fmaxf(v2.x, v2.y), fmaxf(v2.z, v2.w)));
        m = fmaxf(m, fmaxf(fmaxf(v3.x, v3.y), fmaxf(v3.z, v3.w)));
        m = fmaxf(m, fmaxf(fmaxf(v4.x, v4.y), fmaxf(v4.z, v4.w)));
        m = fmaxf(m, fmaxf(fmaxf(v5.x, v5.y), fmaxf(v5.z, v5.w)));
        m = fmaxf(m, fmaxf(fmaxf(v6.x, v6.y), fmaxf(v6.z, v6.w)));
        m = fmaxf(m, fmaxf(vpro, vtail));

        // Wave-64 max butterfly, then block max via LDS broadcast.
        #pragma unroll
        for (int off = 32; off > 0; off >>= 1) m = fmaxf(m, __shfl_xor(m, off));
        if ((t & 63) == 0) sMax[t >> 6] = m;
        sync_lds_only();                                   // barrier A (no vmcnt drain)
        const float M = fmaxf(fmaxf(sMax[0], sMax[1]), fmaxf(sMax[2], sMax[3]));

        // ---- Phase B: first index equal to M, scanning held regs high->low ----
        int fi = 0x7fffffff;
        if (vtail == M) fi = tailStart + t;
        {
            const int b6 = pro + 4 * i6;
            if (v6.w == M) fi = b6 + 3;
            if (v6.z == M) fi = b6 + 2;
            if (v6.y == M) fi = b6 + 1;
            if (v6.x == M) fi = b6;
        }
        #define SCAN(v, k)                                   \
            {   const int b = pro + 4 * (t + 256 * (k));     \
                if ((v).w == M) fi = b + 3;                  \
                if ((v).z == M) fi = b + 2;                  \
                if ((v).y == M) fi = b + 1;                  \
                if ((v).x == M) fi = b;                      }
        SCAN(v5, 5) SCAN(v4, 4) SCAN(v3, 3) SCAN(v2, 2) SCAN(v1, 1) SCAN(v0, 0)
        #undef SCAN
        if (vpro == M) fi = t;

        // Wave min butterfly, then block min -> label (first occurrence).
        #pragma unroll
        for (int off = 32; off > 0; off >>= 1) fi = min(fi, __shfl_xor(fi, off));
        if ((t & 63) == 0) sFi[t >> 6] = fi;
        sync_lds_only();                                   // barrier B (no vmcnt drain)
        const int lab = min(min(sFi[0], sFi[1]), min(sFi[2], sFi[3]));

        // ---- dist via wave 0: lanes 0..23 each load one float4 of f and c ----
        // f and c loads issue back-to-back -> latencies overlap. No trailing
        // barrier (R10): waves 1-3 proceed into row 1 while wave 0 finishes.
        if (t < 64) {
            float sf2 = 0.f, sc2 = 0.f, sfc = 0.f;
            if (t < 24) {   // 24 * float4 = 96 floats; rows are 384B-aligned
                const float4* f4 = (const float4*)(features + (size_t)n   * FD);
                const float4* c4 = (const float4*)(centers  + (size_t)lab * FD);
                float4 f = f4[t], c = c4[t];
                sf2 = f.x*f.x + f.y*f.y + f.z*f.z + f.w*f.w;
                sc2 = c.x*c.x + c.y*c.y + c.z*c.z + c.w*c.w;
                sfc = f.x*c.x + f.y*c.y + f.z*c.z + f.w*c.w;
            }
            #pragma unroll
            for (int off = 16; off > 0; off >>= 1) {   // xor<32 stays in 0..31
                sf2 += __shfl_xor(sf2, off);
                sc2 += __shfl_xor(sc2, off);
                sfc += __shfl_xor(sfc, off);
            }
            if (t == 0) {
                float dist = sf2 + sc2 - 2.0f * sfc;
                dist = fminf(fmaxf(dist, 1e-12f), 1e12f);
                row_out[n] = dist;
            }
        }
    }
}

// Deterministic final reduce (single block, fixed order -> bit-identical replays).
__global__ __launch_bounds__(256) void centerloss_reduce_kernel(
    const float* __restrict__ row_out,
    float* __restrict__ out)
{
    const int t = threadIdx.x;
    const float4* r4 = (const float4*)row_out;   // NROW/4 = 1024 float4s
    float s = 0.f;
    #pragma unroll
    for (int k = 0; k < NROW / 4 / 256; ++k) {
        float4 v = r4[t + 256 * k];
        s += v.x + v.y + v.z + v.w;
    }
    #pragma unroll
    for (int off = 32; off > 0; off >>= 1) s += __shfl_xor(s, off);

    __shared__ float sv[4];
    if ((t & 63) == 0) sv[t >> 6] = s;
    __syncthreads();
    if (t == 0)
        out[0] = (sv[0] + sv[1] + sv[2] + sv[3]) / (float)NROW
                 + (float)(NC - 1) * 1e-12f;
}

extern "C" void kernel_launch(void* const* d_in, const int* in_sizes, int n_in,
                              void* d_out, int out_size, void* d_ws, size_t ws_size,
                              hipStream_t stream) {
    const float* features = (const float*)d_in[0];
    const float* predicts = (const float*)d_in[1];
    const float* centers  = (const float*)d_in[2];
    float* out = (float*)d_out;
    float* ws  = (float*)d_ws;   // NROW floats of per-row clipped distances

    centerloss_row_kernel<<<NROW / RPB, 256, 0, stream>>>(features, predicts, centers, ws);
    centerloss_reduce_kernel<<<1, 256, 0, stream>>>(ws, out);
}